// Round 4
// baseline (274.389 us; speedup 1.0000x reference)
//
#include <hip/hip_runtime.h>

typedef _Float16 half8 __attribute__((ext_vector_type(8)));
typedef _Float16 half4 __attribute__((ext_vector_type(4)));
typedef float f32x4 __attribute__((ext_vector_type(4)));

constexpr int B = 2, L = 2048, S = 2048, H = 16, E = 64, D = 64;
constexpr int BM = 128;  // Q rows per workgroup (32 per wave)
constexpr int BN = 64;   // K/V rows per iteration
constexpr int NTI = S / BN;
constexpr float CS = 0.125f * 1.44269504089f;  // scale * log2(e)

// ============================================================================
// Pre-pass: fp32 -> f16 conversion + V transpose + mask prescale, into d_ws.
//   ws layout: Kh [b][h][s][e] f16 (8 MB) | VTh [b][h][d][s] f16 (8 MB)
//              | Mh [l][s] f16, prescaled by CS (8 MB)
// ============================================================================
constexpr size_t KH_HALFS = (size_t)B * H * S * E;   // 4194304
constexpr size_t VT_HALFS = (size_t)B * H * D * S;   // 4194304
constexpr size_t MH_HALFS = (size_t)L * S;           // 4194304
constexpr size_t WS_NEED  = (KH_HALFS + VT_HALFS + MH_HALFS) * 2;  // 25165824 B

__global__ __launch_bounds__(256, 4)
void prep_kernel(const float* __restrict__ Kg, const float* __restrict__ Vg,
                 const float* __restrict__ Mg, _Float16* __restrict__ ws)
{
    _Float16* Kh  = ws;
    _Float16* VTh = ws + KH_HALFS;
    _Float16* Mh  = ws + KH_HALFS + VT_HALFS;
    const int tid = threadIdx.x;
    const int bid = blockIdx.x;

    if (bid < 4096) {
        // ---- K convert: [b][s][h][e] f32 -> [b][h][s][e] f16 ----
        const int idx = bid * 256 + tid;          // 1 float4 per thread
        const int e   = (idx & 15) * 4;
        const int s   = (idx >> 4) & 2047;
        const int hb  = idx >> 15;
        const int h   = hb & 15, b = hb >> 4;
        const float4 v = *(const float4*)(Kg + ((size_t)(b * S + s)) * (H * E) + h * E + e);
        half4 o = {(_Float16)v.x, (_Float16)v.y, (_Float16)v.z, (_Float16)v.w};
        *(half4*)(Kh + ((size_t)((b * H + h) * S + s)) * E + e) = o;
    } else if (bid < 8192) {
        // ---- mask convert + prescale: f32 -> f16 * CS ----
        const size_t idx = (size_t)(bid - 4096) * 256 + tid;  // 1 float4 per thread
        const float4 v = *(const float4*)(Mg + idx * 4);
        half4 o = {(_Float16)(v.x * CS), (_Float16)(v.y * CS),
                   (_Float16)(v.z * CS), (_Float16)(v.w * CS)};
        *(half4*)(Mh + idx * 4) = o;
    } else {
        // ---- V transpose: [b][s][h][d] f32 -> [b][h][d][s] f16, 64x64 LDS tile ----
        __shared__ _Float16 tile[64][68];
        const int bid2 = bid - 8192;
        const int sblk = bid2 & 31;
        const int h    = (bid2 >> 5) & 15;
        const int b    = bid2 >> 9;
        const int ts = tid >> 4, d4 = (tid & 15) << 2;
        #pragma unroll
        for (int ii = 0; ii < 4; ++ii) {
            const int s = sblk * 64 + ts + ii * 16;
            const float4 v = *(const float4*)(Vg + ((size_t)(b * S + s)) * (H * D) + h * D + d4);
            #pragma unroll
            for (int j = 0; j < 4; ++j)
                tile[d4 + j][ts + ii * 16] = (_Float16)((&v.x)[j]);
        }
        __syncthreads();
        const int d = tid >> 2, sc = (tid & 3) << 4;
        #pragma unroll
        for (int c = 0; c < 4; ++c) {
            half4 o;
            #pragma unroll
            for (int k = 0; k < 4; ++k) o[k] = tile[d][sc + c * 4 + k];
            *(half4*)(VTh + ((size_t)((b * H + h) * D + d) << 11) + sblk * 64 + sc + c * 4) = o;
        }
    }
}

// ============================================================================
// Main kernel: barrier-free. K/V/mask frags loaded directly from f16 global
// (L2-resident); only the P roundtrip uses LDS (wave-private, XOR-swizzled).
// ============================================================================

// One K/V tile step. KC: current K frags (in regs). KN: prefetch dest for T+1.
// MC/MN: mask half4[8] current / prefetch.
#define TILE_STEP(KC, KN, MC, MN, T)                                                        \
{                                                                                           \
    const int s0_ = (T) * BN;                                                               \
    /* V-frag loads for this tile (consumed in PV; hidden under QK+softmax) */              \
    _Pragma("unroll")                                                                       \
    for (int ks = 0; ks < 2; ++ks)                                                          \
        _Pragma("unroll")                                                                   \
        for (int dt = 0; dt < 4; ++dt)                                                      \
            vfr[ks*4+dt] = *(const half8*)(vt_bh + ((size_t)(dt*16 + lq) << 11)             \
                                           + s0_ + ks*32 + quad*8);                         \
    /* S^T = K Q^T from prefetched KC */                                                    \
    f32x4 sf[2][4];                                                                         \
    __builtin_amdgcn_s_setprio(1);                                                          \
    _Pragma("unroll")                                                                       \
    for (int nt = 0; nt < 4; ++nt) {                                                        \
        _Pragma("unroll")                                                                   \
        for (int g = 0; g < 2; ++g) {                                                       \
            f32x4 acc = (f32x4){0.f, 0.f, 0.f, 0.f};                                        \
            acc = __builtin_amdgcn_mfma_f32_16x16x32_f16(KC[nt*2+0], qf[g][0], acc, 0,0,0); \
            acc = __builtin_amdgcn_mfma_f32_16x16x32_f16(KC[nt*2+1], qf[g][1], acc, 0,0,0); \
            sf[g][nt] = acc;                                                                \
        }                                                                                   \
    }                                                                                       \
    __builtin_amdgcn_s_setprio(0);                                                          \
    /* prefetch K frags for tile T+1 (hidden under softmax+PV) */                           \
    if ((T) + 1 < NTI) {                                                                    \
        const int s1_ = s0_ + BN;                                                           \
        _Pragma("unroll")                                                                   \
        for (int nt = 0; nt < 4; ++nt)                                                      \
            _Pragma("unroll")                                                               \
            for (int eh = 0; eh < 2; ++eh)                                                  \
                KN[nt*2+eh] = *(const half8*)(kh_bh + ((size_t)(s1_ + nt*16 + lq) << 6)     \
                                              + eh*32 + quad*8);                            \
    }                                                                                       \
    /* softmax: p = exp2(sf + mask_prescaled); swizzled b64 stores to sP */                 \
    _Pragma("unroll")                                                                       \
    for (int g = 0; g < 2; ++g) {                                                           \
        const int row = g*16 + lq;                                                          \
        char* prow = (char*)&sP[wave][row][0];                                              \
        _Pragma("unroll")                                                                   \
        for (int nt = 0; nt < 4; ++nt) {                                                    \
            half4 hp;                                                                       \
            _Pragma("unroll")                                                               \
            for (int r = 0; r < 4; ++r) {                                                   \
                float lg = sf[g][nt][r] + (float)MC[g*4+nt][r];                             \
                float p  = __builtin_amdgcn_exp2f(lg);                                      \
                lsum[g] += p;                                                               \
                hp[r] = (_Float16)p;                                                        \
            }                                                                               \
            *(half4*)(prow + ((((2*nt + (quad>>1)) ^ (lq&7)) << 4) + ((quad&1) << 3))) = hp;\
        }                                                                                   \
    }                                                                                       \
    /* prefetch mask for tile T+1 (L2/L3; hidden under PV + next QK) */                     \
    if ((T) + 1 < NTI) {                                                                    \
        const int s1_ = s0_ + BN;                                                           \
        _Pragma("unroll")                                                                   \
        for (int g = 0; g < 2; ++g)                                                         \
            _Pragma("unroll")                                                               \
            for (int nt = 0; nt < 4; ++nt)                                                  \
                MN[g*4+nt] = *(const half4*)(mrow0 + ((size_t)g << 15)                      \
                                             + s1_ + nt*16 + quad*4);                       \
    }                                                                                       \
    /* O += P V (A = sP swizzled b128 reads, B = vfr regs) */                               \
    __builtin_amdgcn_s_setprio(1);                                                          \
    _Pragma("unroll")                                                                       \
    for (int ks = 0; ks < 2; ++ks) {                                                        \
        half8 pf0 = *(const half8*)((char*)&sP[wave][     lq][0]                            \
                                    + (((4*ks + quad) ^ (lq&7)) << 4));                     \
        half8 pf1 = *(const half8*)((char*)&sP[wave][16 + lq][0]                            \
                                    + (((4*ks + quad) ^ (lq&7)) << 4));                     \
        _Pragma("unroll")                                                                   \
        for (int dt = 0; dt < 4; ++dt) {                                                    \
            oacc[0][dt] = __builtin_amdgcn_mfma_f32_16x16x32_f16(pf0, vfr[ks*4+dt],         \
                                                                 oacc[0][dt], 0,0,0);       \
            oacc[1][dt] = __builtin_amdgcn_mfma_f32_16x16x32_f16(pf1, vfr[ks*4+dt],         \
                                                                 oacc[1][dt], 0,0,0);       \
        }                                                                                   \
    }                                                                                       \
    __builtin_amdgcn_s_setprio(0);                                                          \
}

__global__ __launch_bounds__(256, 2)
void fa2_kernel(const float* __restrict__ Qg, const _Float16* __restrict__ ws,
                float* __restrict__ Og)
{
    // sP: per-wave P tile [32 q-rows][64 s], 64-half rows with 16B-chunk XOR swizzle
    __shared__ _Float16 sP[4][32][64];

    const _Float16* Kh  = ws;
    const _Float16* VTh = ws + KH_HALFS;
    const _Float16* Mh  = ws + KH_HALFS + VT_HALFS;

    const int tid  = threadIdx.x;
    const int wave = tid >> 6;
    const int lane = tid & 63;
    const int quad = lane >> 4;
    const int lq   = lane & 15;

    // XCD-aware decode: WG i -> XCD i%8; each XCD owns 4 (b,h) -> f16 K/V = 2 MB < L2.
    const int i  = blockIdx.x;             // grid = 512
    const int bh = (i & 7) * 4 + ((i >> 3) & 3);
    const int qb = i >> 5;
    const int b  = bh >> 4;
    const int h  = bh & 15;
    const int q0 = qb * BM;

    const int rowStride = H * E;  // 1024 floats
    const size_t qbase = ((size_t)b * L) * rowStride + h * E;

    const _Float16* kh_bh = Kh  + ((size_t)(b * H + h) << 17);  // S*E halves per bh
    const _Float16* vt_bh = VTh + ((size_t)(b * H + h) << 17);  // D*S halves per bh
    const _Float16* mrow0 = Mh  + ((size_t)(q0 + wave * 32 + lq) << 11);  // +g*16 rows via <<15

    // ---- Q fragments (2 q-groups), prescaled by CS ----
    half8 qf[2][2];
    #pragma unroll
    for (int g = 0; g < 2; ++g) {
        const float* qp = Qg + qbase + (size_t)(q0 + wave*32 + g*16 + lq) * rowStride + quad*8;
        #pragma unroll
        for (int ks = 0; ks < 2; ++ks)
            #pragma unroll
            for (int j = 0; j < 8; ++j)
                qf[g][ks][j] = (_Float16)(qp[ks*32 + j] * CS);
    }

    float lsum[2] = {0.f, 0.f};
    f32x4 oacc[2][4];
    #pragma unroll
    for (int g = 0; g < 2; ++g)
        #pragma unroll
        for (int dt = 0; dt < 4; ++dt) oacc[g][dt] = (f32x4){0.f, 0.f, 0.f, 0.f};

    half8 kfA[8], kfB[8], vfr[8];
    half4 mA[8], mB[8];

    // ---- prologue: K frags + mask for tile 0 ----
    #pragma unroll
    for (int nt = 0; nt < 4; ++nt)
        #pragma unroll
        for (int eh = 0; eh < 2; ++eh)
            kfA[nt*2+eh] = *(const half8*)(kh_bh + ((size_t)(nt*16 + lq) << 6) + eh*32 + quad*8);
    #pragma unroll
    for (int g = 0; g < 2; ++g)
        #pragma unroll
        for (int nt = 0; nt < 4; ++nt)
            mA[g*4+nt] = *(const half4*)(mrow0 + ((size_t)g << 15) + nt*16 + quad*4);

    for (int tt = 0; tt < NTI; tt += 2) {
        TILE_STEP(kfA, kfB, mA, mB, tt);
        TILE_STEP(kfB, kfA, mB, mA, tt + 1);
    }

    // ---- epilogue per q-group: l reduce across quads, O /= l, store fp32 ----
    #pragma unroll
    for (int g = 0; g < 2; ++g) {
        float l = lsum[g];
        l += __shfl_xor(l, 16);
        l += __shfl_xor(l, 32);
        #pragma unroll
        for (int r = 0; r < 4; ++r) {
            float l_bc = __shfl(l, quad*4 + r, 16);
            float inv = 1.f / l_bc;
            float* orow = Og + qbase + (size_t)(q0 + wave*32 + g*16 + quad*4 + r) * rowStride;
            #pragma unroll
            for (int dt = 0; dt < 4; ++dt)
                orow[dt*16 + lq] = oacc[g][dt][r] * inv;
        }
    }
}

// ============================================================================
// Fallback (round-3 kernel, unchanged) for the case ws_size < WS_NEED.
// ============================================================================
constexpr int LDT = 72;

__global__ __launch_bounds__(256, 2)
void fa_fb_kernel(const float* __restrict__ Qg, const float* __restrict__ Kg,
                  const float* __restrict__ Vg, const float* __restrict__ Mg,
                  float* __restrict__ Og)
{
    __shared__ _Float16 sK[BN][LDT];
    __shared__ _Float16 sV[D][LDT];
    __shared__ _Float16 sP[4][32][LDT];

    const int tid  = threadIdx.x;
    const int wave = tid >> 6;
    const int lane = tid & 63;
    const int quad = lane >> 4;
    const int lq   = lane & 15;

    const int i  = blockIdx.x;
    const int bh = (i & 7) * 4 + ((i >> 3) & 3);
    const int qb = i >> 5;
    const int b  = bh >> 4;
    const int h  = bh & 15;
    const int q0 = qb * BM;

    const int rowStride = H * E;
    const size_t qbase = ((size_t)b * L) * rowStride + h * E;
    const size_t kbase = ((size_t)b * S) * rowStride + h * E;

    half8 qf[2][2];
    #pragma unroll
    for (int g = 0; g < 2; ++g) {
        const float* qp = Qg + qbase + (size_t)(q0 + wave*32 + g*16 + lq) * rowStride + quad*8;
        #pragma unroll
        for (int ks = 0; ks < 2; ++ks)
            #pragma unroll
            for (int j = 0; j < 8; ++j)
                qf[g][ks][j] = (_Float16)(qp[ks*32 + j] * CS);
    }

    const float* mrow0 = Mg + (size_t)(q0 + wave*32 + lq) * S;

    float lsum[2] = {0.f, 0.f};
    f32x4 oacc[2][4];
    #pragma unroll
    for (int g = 0; g < 2; ++g)
        #pragma unroll
        for (int dt = 0; dt < 4; ++dt) oacc[g][dt] = (f32x4){0.f, 0.f, 0.f, 0.f};

    const int db = tid & 15;
    const int sb = tid >> 4;
    const float* vbase = Vg + kbase + (size_t)(sb*4) * rowStride + db*4;
    const float* krow  = Kg + kbase + (size_t)(tid >> 4) * rowStride + (tid & 15)*4;
    const int voff = (((sb >> 1) ^ (db >> 1)) << 3) + ((sb & 1) << 2);

    float4 kreg[4], vreg[4], mreg[2][4];

    #pragma unroll
    for (int ii = 0; ii < 4; ++ii)
        kreg[ii] = *(const float4*)(krow + (size_t)(ii*16) * rowStride);
    #pragma unroll
    for (int j = 0; j < 4; ++j)
        vreg[j] = *(const float4*)(vbase + (size_t)j * rowStride);
    #pragma unroll
    for (int g = 0; g < 2; ++g)
        #pragma unroll
        for (int nt = 0; nt < 4; ++nt)
            mreg[g][nt] = *(const float4*)(mrow0 + (size_t)g*16*S + nt*16 + quad*4);

    #pragma unroll
    for (int ii = 0; ii < 4; ++ii) {
        half4 hk = {(_Float16)kreg[ii].x, (_Float16)kreg[ii].y,
                    (_Float16)kreg[ii].z, (_Float16)kreg[ii].w};
        *(half4*)&sK[(tid >> 4) + ii*16][(tid & 15)*4] = hk;
    }
    #pragma unroll
    for (int j = 0; j < 4; ++j) {
        half4 hv = { (_Float16)((&vreg[0].x)[j]), (_Float16)((&vreg[1].x)[j]),
                     (_Float16)((&vreg[2].x)[j]), (_Float16)((&vreg[3].x)[j]) };
        *(half4*)&sV[db*4 + j][voff] = hv;
    }
    __syncthreads();

    for (int t = 0; t < NTI; ++t) {
        if (t + 1 < NTI) {
            const int s1 = (t + 1) * BN;
            #pragma unroll
            for (int ii = 0; ii < 4; ++ii)
                kreg[ii] = *(const float4*)(krow + (size_t)(s1 + ii*16) * rowStride);
            #pragma unroll
            for (int j = 0; j < 4; ++j)
                vreg[j] = *(const float4*)(vbase + (size_t)(s1 + j) * rowStride);
        }

        f32x4 sf[2][4];
        __builtin_amdgcn_s_setprio(1);
        #pragma unroll
        for (int nt = 0; nt < 4; ++nt) {
            half8 kf0 = *(const half8*)&sK[nt*16 + lq][ 0 + quad*8];
            half8 kf1 = *(const half8*)&sK[nt*16 + lq][32 + quad*8];
            #pragma unroll
            for (int g = 0; g < 2; ++g) {
                f32x4 acc = (f32x4){0.f, 0.f, 0.f, 0.f};
                acc = __builtin_amdgcn_mfma_f32_16x16x32_f16(kf0, qf[g][0], acc, 0, 0, 0);
                acc = __builtin_amdgcn_mfma_f32_16x16x32_f16(kf1, qf[g][1], acc, 0, 0, 0);
                sf[g][nt] = acc;
            }
        }
        __builtin_amdgcn_s_setprio(0);

        #pragma unroll
        for (int g = 0; g < 2; ++g)
            #pragma unroll
            for (int nt = 0; nt < 4; ++nt) {
                half4 hp;
                #pragma unroll
                for (int r = 0; r < 4; ++r) {
                    float lg = fmaf((&mreg[g][nt].x)[r], CS, sf[g][nt][r]);
                    float p  = __builtin_amdgcn_exp2f(lg);
                    lsum[g] += p;
                    hp[r] = (_Float16)p;
                }
                *(half4*)&sP[wave][g*16 + lq][nt*16 + quad*4] = hp;
            }

        if (t + 1 < NTI) {
            const int s1 = (t + 1) * BN;
            #pragma unroll
            for (int g = 0; g < 2; ++g)
                #pragma unroll
                for (int nt = 0; nt < 4; ++nt)
                    mreg[g][nt] = *(const float4*)(mrow0 + (size_t)g*16*S + s1 + nt*16 + quad*4);
        }

        __builtin_amdgcn_s_setprio(1);
        #pragma unroll
        for (int ks = 0; ks < 2; ++ks) {
            half8 pf0 = *(const half8*)&sP[wave][ 0 + lq][ks*32 + quad*8];
            half8 pf1 = *(const half8*)&sP[wave][16 + lq][ks*32 + quad*8];
            #pragma unroll
            for (int dt = 0; dt < 4; ++dt) {
                const int vrow = dt*16 + lq;
                const int phys = (ks*4 + quad) ^ ((vrow >> 3) & 7);
                half8 vf = *(const half8*)&sV[vrow][phys << 3];
                oacc[0][dt] = __builtin_amdgcn_mfma_f32_16x16x32_f16(pf0, vf, oacc[0][dt], 0, 0, 0);
                oacc[1][dt] = __builtin_amdgcn_mfma_f32_16x16x32_f16(pf1, vf, oacc[1][dt], 0, 0, 0);
            }
        }
        __builtin_amdgcn_s_setprio(0);

        if (t + 1 < NTI) {
            __syncthreads();
            #pragma unroll
            for (int ii = 0; ii < 4; ++ii) {
                half4 hk = {(_Float16)kreg[ii].x, (_Float16)kreg[ii].y,
                            (_Float16)kreg[ii].z, (_Float16)kreg[ii].w};
                *(half4*)&sK[(tid >> 4) + ii*16][(tid & 15)*4] = hk;
            }
            #pragma unroll
            for (int j = 0; j < 4; ++j) {
                half4 hv = { (_Float16)((&vreg[0].x)[j]), (_Float16)((&vreg[1].x)[j]),
                             (_Float16)((&vreg[2].x)[j]), (_Float16)((&vreg[3].x)[j]) };
                *(half4*)&sV[db*4 + j][voff] = hv;
            }
            __syncthreads();
        }
    }

    #pragma unroll
    for (int g = 0; g < 2; ++g) {
        float l = lsum[g];
        l += __shfl_xor(l, 16);
        l += __shfl_xor(l, 32);
        #pragma unroll
        for (int r = 0; r < 4; ++r) {
            float l_bc = __shfl(l, quad*4 + r, 16);
            float inv = 1.f / l_bc;
            float* orow = Og + qbase + (size_t)(q0 + wave*32 + g*16 + quad*4 + r) * rowStride;
            #pragma unroll
            for (int dt = 0; dt < 4; ++dt)
                orow[dt*16 + lq] = oacc[g][dt][r] * inv;
        }
    }
}

extern "C" void kernel_launch(void* const* d_in, const int* in_sizes, int n_in,
                              void* d_out, int out_size, void* d_ws, size_t ws_size,
                              hipStream_t stream) {
    const float* Qg = (const float*)d_in[0];
    const float* Kg = (const float*)d_in[1];
    const float* Vg = (const float*)d_in[2];
    const float* Mg = (const float*)d_in[3];
    float* Og = (float*)d_out;

    if (ws_size >= WS_NEED && d_ws != nullptr) {
        _Float16* ws = (_Float16*)d_ws;
        prep_kernel<<<dim3(4096 + 4096 + 1024), 256, 0, stream>>>(Kg, Vg, Mg, ws);
        fa2_kernel<<<dim3((L / BM) * B * H), 256, 0, stream>>>(Qg, ws, Og);
    } else {
        fa_fb_kernel<<<dim3((L / BM) * B * H), 256, 0, stream>>>(Qg, Kg, Vg, Mg, Og);
    }
}

// Round 5
// 175.885 us; speedup vs baseline: 1.5601x; 1.5601x over previous
//
#include <hip/hip_runtime.h>
#include <stdint.h>

typedef _Float16 half8 __attribute__((ext_vector_type(8)));
typedef _Float16 half4 __attribute__((ext_vector_type(4)));
typedef float f32x4 __attribute__((ext_vector_type(4)));

constexpr int B = 2, L = 2048, S = 2048, H = 16, E = 64, D = 64;
constexpr int BM = 128;  // Q rows per workgroup (32 per wave)
constexpr int BN = 64;   // K/V rows per iteration
constexpr int NTI = S / BN;
constexpr float CS = 0.125f * 1.44269504089f;  // scale * log2(e)

// ws layout: Kh [bh][s][e] f16, 16B-chunk XOR-swizzled within each 128B row
//            (slot = chunk ^ (s&7)) | VTh [bh][d][s] f16, swizzled per 64-half
//            segment (slot = chunk ^ (d&7)) | Mh [l][s] f16 prescaled by CS (linear)
constexpr size_t KH_HALFS = (size_t)B * H * S * E;
constexpr size_t VT_HALFS = (size_t)B * H * D * S;
constexpr size_t MH_HALFS = (size_t)L * S;
constexpr size_t WS_NEED  = (KH_HALFS + VT_HALFS + MH_HALFS) * 2;  // 24 MB

// ============================================================================
// Pre-pass (verified structure from round 4; swizzle baked into K/V layout,
// V-transpose writes widened to 2x16B per thread covering full 128B segments)
// ============================================================================
__global__ __launch_bounds__(256, 4)
void prep_kernel(const float* __restrict__ Kg, const float* __restrict__ Vg,
                 const float* __restrict__ Mg, _Float16* __restrict__ ws)
{
    _Float16* Kh  = ws;
    _Float16* VTh = ws + KH_HALFS;
    _Float16* Mh  = ws + KH_HALFS + VT_HALFS;
    const int tid = threadIdx.x;
    const int bid = blockIdx.x;

    if (bid < 2048) {
        // ---- K: [b][s][h][e] f32 -> [bh][s][slot] f16, slot = chunk^(s&7) ----
        const int idx = bid * 256 + tid;       // one half8 chunk per thread
        const int c   = idx & 7;
        const int s   = (idx >> 3) & 2047;
        const int bh  = idx >> 14;
        const int b   = bh >> 4, h = bh & 15;
        const float* src = Kg + ((size_t)(b * S + s)) * (H * E) + h * E + c * 8;
        const float4 v0 = *(const float4*)(src);
        const float4 v1 = *(const float4*)(src + 4);
        half8 o = {(_Float16)v0.x, (_Float16)v0.y, (_Float16)v0.z, (_Float16)v0.w,
                   (_Float16)v1.x, (_Float16)v1.y, (_Float16)v1.z, (_Float16)v1.w};
        *(half8*)(Kh + (((size_t)bh * S + s) << 6) + ((c ^ (s & 7)) * 8)) = o;
    } else if (bid < 4096) {
        // ---- mask: f32 -> f16 * CS, linear ----
        const size_t idx = (size_t)(bid - 2048) * 256 + tid;  // one half8
        const float* src = Mg + idx * 8;
        const float4 v0 = *(const float4*)(src);
        const float4 v1 = *(const float4*)(src + 4);
        half8 o = {(_Float16)(v0.x*CS), (_Float16)(v0.y*CS), (_Float16)(v0.z*CS),
                   (_Float16)(v0.w*CS), (_Float16)(v1.x*CS), (_Float16)(v1.y*CS),
                   (_Float16)(v1.z*CS), (_Float16)(v1.w*CS)};
        *(half8*)(Mh + idx * 8) = o;
    } else {
        // ---- V: [b][s][h][d] f32 -> [bh][d][seg slot] f16, slot = chunk^(d&7) ----
        __shared__ _Float16 tile[64][72];
        const int bid2 = bid - 4096;
        const int sblk = bid2 & 31;
        const int h    = (bid2 >> 5) & 15;
        const int b    = bid2 >> 9;
        const int ts = tid >> 4, d4 = (tid & 15) << 2;
        #pragma unroll
        for (int ii = 0; ii < 4; ++ii) {
            const int sl = ts + ii * 16;
            const float4 v = *(const float4*)(Vg + ((size_t)(b * S + sblk*64 + sl)) * (H * D) + h * D + d4);
            #pragma unroll
            for (int j = 0; j < 4; ++j)
                tile[d4 + j][sl] = (_Float16)((&v.x)[j]);
        }
        __syncthreads();
        const int d = tid >> 2, cp = tid & 3;   // 4 threads cover row d's 128B segment
        _Float16* drow = VTh + (((size_t)(b * H + h) * D + d) << 11) + sblk * 64;
        #pragma unroll
        for (int k = 0; k < 2; ++k) {
            const int chunk = cp * 2 + k;
            half8 o;
            #pragma unroll
            for (int j = 0; j < 8; ++j) o[j] = tile[d][chunk * 8 + j];
            *(half8*)(drow + ((chunk ^ (d & 7)) * 8)) = o;
        }
    }
}

// ============================================================================
// Main kernel: double-buffered sK/sV staged via global_load_lds (linear DMA of
// pre-swizzled ws rows), ONE barrier per iteration, conflict-free XOR reads.
// ============================================================================
__device__ __forceinline__ void gload16(const _Float16* g, const _Float16* l) {
    __builtin_amdgcn_global_load_lds(
        (const __attribute__((address_space(1))) uint32_t*)(uintptr_t)(g),
        (__attribute__((address_space(3))) uint32_t*)(uintptr_t)(l),
        16, 0, 0);
}

// Wave w stages rows [16w,16w+16) of both tiles: 2 gload instrs each (16B/lane).
#define STAGE(BUF, S0)                                                          \
{                                                                               \
    _Pragma("unroll")                                                           \
    for (int ii = 0; ii < 2; ++ii) {                                            \
        const int r = wave * 16 + ii * 8;                                       \
        gload16(kh_bh + ((size_t)((S0) + r + (lane >> 3)) << 6) + (lane & 7)*8, \
                &sK[BUF][r][0]);                                                \
        gload16(vt_bh + ((size_t)(r + (lane >> 3)) << 11) + (S0) + (lane & 7)*8,\
                &sV[BUF][r][0]);                                                \
    }                                                                           \
}

#define TILE_STEP(BUF, MC, MN, T)                                                           \
{                                                                                           \
    if ((T) + 1 < NTI) STAGE((BUF) ^ 1, ((T) + 1) * BN)                                     \
    /* S^T = K Q^T; K-frags from swizzled sK, each feeds both q-groups */                   \
    f32x4 sf[2][4];                                                                         \
    __builtin_amdgcn_s_setprio(1);                                                          \
    _Pragma("unroll")                                                                       \
    for (int nt = 0; nt < 4; ++nt) {                                                        \
        half8 kf0 = *(const half8*)&sK[BUF][nt*16 + lq][((    quad) ^ (lq & 7)) * 8];       \
        half8 kf1 = *(const half8*)&sK[BUF][nt*16 + lq][((4 + quad) ^ (lq & 7)) * 8];       \
        _Pragma("unroll")                                                                   \
        for (int g = 0; g < 2; ++g) {                                                       \
            f32x4 acc = (f32x4){0.f, 0.f, 0.f, 0.f};                                        \
            acc = __builtin_amdgcn_mfma_f32_16x16x32_f16(kf0, qf[g][0], acc, 0, 0, 0);      \
            acc = __builtin_amdgcn_mfma_f32_16x16x32_f16(kf1, qf[g][1], acc, 0, 0, 0);      \
            sf[g][nt] = acc;                                                                \
        }                                                                                   \
    }                                                                                       \
    __builtin_amdgcn_s_setprio(0);                                                          \
    /* softmax: p = exp2(sf + mask); swizzled b64 stores to sP */                           \
    _Pragma("unroll")                                                                       \
    for (int g = 0; g < 2; ++g) {                                                           \
        _Float16* prow = &sP[wave][g*16 + lq][0];                                           \
        _Pragma("unroll")                                                                   \
        for (int nt = 0; nt < 4; ++nt) {                                                    \
            half4 hp;                                                                       \
            _Pragma("unroll")                                                               \
            for (int r = 0; r < 4; ++r) {                                                   \
                float lg = sf[g][nt][r] + (float)MC[g*4 + nt][r];                           \
                float p  = __builtin_amdgcn_exp2f(lg);                                      \
                lsum[g] += p;                                                               \
                hp[r] = (_Float16)p;                                                        \
            }                                                                               \
            *(half4*)(prow + (((2*nt + (quad >> 1)) ^ (lq & 7)) * 8 + (quad & 1) * 4)) = hp;\
        }                                                                                   \
    }                                                                                       \
    /* mask prefetch tile T+1 (L3-resident; drained at the barrier) */                      \
    if ((T) + 1 < NTI) {                                                                    \
        const int s1_ = ((T) + 1) * BN;                                                     \
        _Pragma("unroll")                                                                   \
        for (int g = 0; g < 2; ++g)                                                         \
            _Pragma("unroll")                                                               \
            for (int nt = 0; nt < 4; ++nt)                                                  \
                MN[g*4 + nt] = *(const half4*)(mrow0 + ((size_t)g << 15)                    \
                                               + s1_ + nt*16 + quad*4);                     \
    }                                                                                       \
    /* O += P V from swizzled sP / sV */                                                    \
    __builtin_amdgcn_s_setprio(1);                                                          \
    _Pragma("unroll")                                                                       \
    for (int ks = 0; ks < 2; ++ks) {                                                        \
        half8 pf0 = *(const half8*)&sP[wave][     lq][((4*ks + quad) ^ (lq & 7)) * 8];      \
        half8 pf1 = *(const half8*)&sP[wave][16 + lq][((4*ks + quad) ^ (lq & 7)) * 8];      \
        _Pragma("unroll")                                                                   \
        for (int dt = 0; dt < 4; ++dt) {                                                    \
            half8 vf = *(const half8*)&sV[BUF][dt*16 + lq][((4*ks + quad) ^ (lq & 7)) * 8]; \
            oacc[0][dt] = __builtin_amdgcn_mfma_f32_16x16x32_f16(pf0, vf, oacc[0][dt],0,0,0);\
            oacc[1][dt] = __builtin_amdgcn_mfma_f32_16x16x32_f16(pf1, vf, oacc[1][dt],0,0,0);\
        }                                                                                   \
    }                                                                                       \
    __builtin_amdgcn_s_setprio(0);                                                          \
    if ((T) + 1 < NTI) __syncthreads();  /* drains DMA (vmcnt) + orders buffers */          \
}

__global__ __launch_bounds__(256, 2)
void fa3_kernel(const float* __restrict__ Qg, const _Float16* __restrict__ ws,
                float* __restrict__ Og)
{
    __shared__ _Float16 sK[2][BN][64];   // 16 KB, double-buffered, DMA-filled
    __shared__ _Float16 sV[2][D][64];    // 16 KB
    __shared__ _Float16 sP[4][32][64];   // 16 KB, wave-private, XOR-swizzled

    const _Float16* Kh  = ws;
    const _Float16* VTh = ws + KH_HALFS;
    const _Float16* Mh  = ws + KH_HALFS + VT_HALFS;

    const int tid  = threadIdx.x;
    const int wave = tid >> 6;
    const int lane = tid & 63;
    const int quad = lane >> 4;
    const int lq   = lane & 15;

    // XCD-aware decode: WG i -> XCD i%8; each XCD owns 4 (b,h) -> f16 K/V = 2 MB < L2.
    const int i  = blockIdx.x;             // grid = 512
    const int bh = (i & 7) * 4 + ((i >> 3) & 3);
    const int qb = i >> 5;
    const int b  = bh >> 4;
    const int h  = bh & 15;
    const int q0 = qb * BM;

    const int rowStride = H * E;
    const size_t qbase = ((size_t)b * L) * rowStride + h * E;

    const _Float16* kh_bh = Kh  + ((size_t)(b * H + h) << 17);
    const _Float16* vt_bh = VTh + ((size_t)(b * H + h) << 17);
    const _Float16* mrow0 = Mh  + ((size_t)(q0 + wave * 32 + lq) << 11);

    // ---- Q fragments (2 q-groups), prescaled by CS ----
    half8 qf[2][2];
    #pragma unroll
    for (int g = 0; g < 2; ++g) {
        const float* qp = Qg + qbase + (size_t)(q0 + wave*32 + g*16 + lq) * rowStride + quad*8;
        #pragma unroll
        for (int ks = 0; ks < 2; ++ks)
            #pragma unroll
            for (int j = 0; j < 8; ++j)
                qf[g][ks][j] = (_Float16)(qp[ks*32 + j] * CS);
    }

    float lsum[2] = {0.f, 0.f};
    f32x4 oacc[2][4];
    #pragma unroll
    for (int g = 0; g < 2; ++g)
        #pragma unroll
        for (int dt = 0; dt < 4; ++dt) oacc[g][dt] = (f32x4){0.f, 0.f, 0.f, 0.f};

    half4 mA[8], mB[8];

    // ---- prologue: DMA tile 0 into buf0; mask tile 0 -> regs ----
    STAGE(0, 0)
    #pragma unroll
    for (int g = 0; g < 2; ++g)
        #pragma unroll
        for (int nt = 0; nt < 4; ++nt)
            mA[g*4 + nt] = *(const half4*)(mrow0 + ((size_t)g << 15) + nt*16 + quad*4);
    __syncthreads();

    for (int tt = 0; tt < NTI; tt += 2) {
        TILE_STEP(0, mA, mB, tt)
        TILE_STEP(1, mB, mA, tt + 1)
    }

    // ---- epilogue per q-group: l reduce across quads, O /= l, store fp32 ----
    #pragma unroll
    for (int g = 0; g < 2; ++g) {
        float l = lsum[g];
        l += __shfl_xor(l, 16);
        l += __shfl_xor(l, 32);
        #pragma unroll
        for (int r = 0; r < 4; ++r) {
            float l_bc = __shfl(l, quad*4 + r, 16);
            float inv = 1.f / l_bc;
            float* orow = Og + qbase + (size_t)(q0 + wave*32 + g*16 + quad*4 + r) * rowStride;
            #pragma unroll
            for (int dt = 0; dt < 4; ++dt)
                orow[dt*16 + lq] = oacc[g][dt][r] * inv;
        }
    }
}

// ============================================================================
// Fallback (round-3 kernel, verified 103 us) for ws_size < WS_NEED.
// ============================================================================
constexpr int LDT = 72;

__global__ __launch_bounds__(256, 2)
void fa_fb_kernel(const float* __restrict__ Qg, const float* __restrict__ Kg,
                  const float* __restrict__ Vg, const float* __restrict__ Mg,
                  float* __restrict__ Og)
{
    __shared__ _Float16 sK[BN][LDT];
    __shared__ _Float16 sV[D][LDT];
    __shared__ _Float16 sP[4][32][LDT];

    const int tid  = threadIdx.x;
    const int wave = tid >> 6;
    const int lane = tid & 63;
    const int quad = lane >> 4;
    const int lq   = lane & 15;

    const int i  = blockIdx.x;
    const int bh = (i & 7) * 4 + ((i >> 3) & 3);
    const int qb = i >> 5;
    const int b  = bh >> 4;
    const int h  = bh & 15;
    const int q0 = qb * BM;

    const int rowStride = H * E;
    const size_t qbase = ((size_t)b * L) * rowStride + h * E;
    const size_t kbase = ((size_t)b * S) * rowStride + h * E;

    half8 qf[2][2];
    #pragma unroll
    for (int g = 0; g < 2; ++g) {
        const float* qp = Qg + qbase + (size_t)(q0 + wave*32 + g*16 + lq) * rowStride + quad*8;
        #pragma unroll
        for (int ks = 0; ks < 2; ++ks)
            #pragma unroll
            for (int j = 0; j < 8; ++j)
                qf[g][ks][j] = (_Float16)(qp[ks*32 + j] * CS);
    }

    const float* mrow0 = Mg + (size_t)(q0 + wave*32 + lq) * S;

    float lsum[2] = {0.f, 0.f};
    f32x4 oacc[2][4];
    #pragma unroll
    for (int g = 0; g < 2; ++g)
        #pragma unroll
        for (int dt = 0; dt < 4; ++dt) oacc[g][dt] = (f32x4){0.f, 0.f, 0.f, 0.f};

    const int db = tid & 15;
    const int sb = tid >> 4;
    const float* vbase = Vg + kbase + (size_t)(sb*4) * rowStride + db*4;
    const float* krow  = Kg + kbase + (size_t)(tid >> 4) * rowStride + (tid & 15)*4;
    const int voff = (((sb >> 1) ^ (db >> 1)) << 3) + ((sb & 1) << 2);

    float4 kreg[4], vreg[4], mreg[2][4];

    #pragma unroll
    for (int ii = 0; ii < 4; ++ii)
        kreg[ii] = *(const float4*)(krow + (size_t)(ii*16) * rowStride);
    #pragma unroll
    for (int j = 0; j < 4; ++j)
        vreg[j] = *(const float4*)(vbase + (size_t)j * rowStride);
    #pragma unroll
    for (int g = 0; g < 2; ++g)
        #pragma unroll
        for (int nt = 0; nt < 4; ++nt)
            mreg[g][nt] = *(const float4*)(mrow0 + (size_t)g*16*S + nt*16 + quad*4);

    #pragma unroll
    for (int ii = 0; ii < 4; ++ii) {
        half4 hk = {(_Float16)kreg[ii].x, (_Float16)kreg[ii].y,
                    (_Float16)kreg[ii].z, (_Float16)kreg[ii].w};
        *(half4*)&sK[(tid >> 4) + ii*16][(tid & 15)*4] = hk;
    }
    #pragma unroll
    for (int j = 0; j < 4; ++j) {
        half4 hv = { (_Float16)((&vreg[0].x)[j]), (_Float16)((&vreg[1].x)[j]),
                     (_Float16)((&vreg[2].x)[j]), (_Float16)((&vreg[3].x)[j]) };
        *(half4*)&sV[db*4 + j][voff] = hv;
    }
    __syncthreads();

    for (int t = 0; t < NTI; ++t) {
        if (t + 1 < NTI) {
            const int s1 = (t + 1) * BN;
            #pragma unroll
            for (int ii = 0; ii < 4; ++ii)
                kreg[ii] = *(const float4*)(krow + (size_t)(s1 + ii*16) * rowStride);
            #pragma unroll
            for (int j = 0; j < 4; ++j)
                vreg[j] = *(const float4*)(vbase + (size_t)(s1 + j) * rowStride);
        }

        f32x4 sf[2][4];
        __builtin_amdgcn_s_setprio(1);
        #pragma unroll
        for (int nt = 0; nt < 4; ++nt) {
            half8 kf0 = *(const half8*)&sK[nt*16 + lq][ 0 + quad*8];
            half8 kf1 = *(const half8*)&sK[nt*16 + lq][32 + quad*8];
            #pragma unroll
            for (int g = 0; g < 2; ++g) {
                f32x4 acc = (f32x4){0.f, 0.f, 0.f, 0.f};
                acc = __builtin_amdgcn_mfma_f32_16x16x32_f16(kf0, qf[g][0], acc, 0, 0, 0);
                acc = __builtin_amdgcn_mfma_f32_16x16x32_f16(kf1, qf[g][1], acc, 0, 0, 0);
                sf[g][nt] = acc;
            }
        }
        __builtin_amdgcn_s_setprio(0);

        #pragma unroll
        for (int g = 0; g < 2; ++g)
            #pragma unroll
            for (int nt = 0; nt < 4; ++nt) {
                half4 hp;
                #pragma unroll
                for (int r = 0; r < 4; ++r) {
                    float lg = fmaf((&mreg[g][nt].x)[r], CS, sf[g][nt][r]);
                    float p  = __builtin_amdgcn_exp2f(lg);
                    lsum[g] += p;
                    hp[r] = (_Float16)p;
                }
                *(half4*)&sP[wave][g*16 + lq][nt*16 + quad*4] = hp;
            }

        if (t + 1 < NTI) {
            const int s1 = (t + 1) * BN;
            #pragma unroll
            for (int g = 0; g < 2; ++g)
                #pragma unroll
                for (int nt = 0; nt < 4; ++nt)
                    mreg[g][nt] = *(const float4*)(mrow0 + (size_t)g*16*S + s1 + nt*16 + quad*4);
        }

        __builtin_amdgcn_s_setprio(1);
        #pragma unroll
        for (int ks = 0; ks < 2; ++ks) {
            half8 pf0 = *(const half8*)&sP[wave][ 0 + lq][ks*32 + quad*8];
            half8 pf1 = *(const half8*)&sP[wave][16 + lq][ks*32 + quad*8];
            #pragma unroll
            for (int dt = 0; dt < 4; ++dt) {
                const int vrow = dt*16 + lq;
                const int phys = (ks*4 + quad) ^ ((vrow >> 3) & 7);
                half8 vf = *(const half8*)&sV[vrow][phys << 3];
                oacc[0][dt] = __builtin_amdgcn_mfma_f32_16x16x32_f16(pf0, vf, oacc[0][dt], 0, 0, 0);
                oacc[1][dt] = __builtin_amdgcn_mfma_f32_16x16x32_f16(pf1, vf, oacc[1][dt], 0, 0, 0);
            }
        }
        __builtin_amdgcn_s_setprio(0);

        if (t + 1 < NTI) {
            __syncthreads();
            #pragma unroll
            for (int ii = 0; ii < 4; ++ii) {
                half4 hk = {(_Float16)kreg[ii].x, (_Float16)kreg[ii].y,
                            (_Float16)kreg[ii].z, (_Float16)kreg[ii].w};
                *(half4*)&sK[(tid >> 4) + ii*16][(tid & 15)*4] = hk;
            }
            #pragma unroll
            for (int j = 0; j < 4; ++j) {
                half4 hv = { (_Float16)((&vreg[0].x)[j]), (_Float16)((&vreg[1].x)[j]),
                             (_Float16)((&vreg[2].x)[j]), (_Float16)((&vreg[3].x)[j]) };
                *(half4*)&sV[db*4 + j][voff] = hv;
            }
            __syncthreads();
        }
    }

    #pragma unroll
    for (int g = 0; g < 2; ++g) {
        float l = lsum[g];
        l += __shfl_xor(l, 16);
        l += __shfl_xor(l, 32);
        #pragma unroll
        for (int r = 0; r < 4; ++r) {
            float l_bc = __shfl(l, quad*4 + r, 16);
            float inv = 1.f / l_bc;
            float* orow = Og + qbase + (size_t)(q0 + wave*32 + g*16 + quad*4 + r) * rowStride;
            #pragma unroll
            for (int dt = 0; dt < 4; ++dt)
                orow[dt*16 + lq] = oacc[g][dt][r] * inv;
        }
    }
}

extern "C" void kernel_launch(void* const* d_in, const int* in_sizes, int n_in,
                              void* d_out, int out_size, void* d_ws, size_t ws_size,
                              hipStream_t stream) {
    const float* Qg = (const float*)d_in[0];
    const float* Kg = (const float*)d_in[1];
    const float* Vg = (const float*)d_in[2];
    const float* Mg = (const float*)d_in[3];
    float* Og = (float*)d_out;

    if (ws_size >= WS_NEED && d_ws != nullptr) {
        _Float16* ws = (_Float16*)d_ws;
        prep_kernel<<<dim3(2048 + 2048 + 1024), 256, 0, stream>>>(Kg, Vg, Mg, ws);
        fa3_kernel<<<dim3((L / BM) * B * H), 256, 0, stream>>>(Qg, ws, Og);
    } else {
        fa_fb_kernel<<<dim3((L / BM) * B * H), 256, 0, stream>>>(Qg, Kg, Vg, Mg, Og);
    }
}